// Round 14
// baseline (45.881 us; speedup 1.0000x reference)
//
#include <hip/hip_runtime.h>

// RetinaNet target encoder for MI355X — round 14: atomic-free, 3-kernel chain.
//   - BLK=512 (2 priors/thread): GT LDS broadcasts amortized over 2 IoUs
//   - GT data packed float4(box) + float2(area, idx): 2 LDS reads/row (was 5)
//   - NO atomics in fused, NO init kernel: per-chunk part1c plain stores
//     (encode reduces 16 chunks), per-block partGc slices via LDS swin
//     (rs reduces 96 blocks, then 1024 atomicMax total)
//   - GT_PER_BLK=64, 1-wave compaction (round-12 style; round-13 reverted)
//
// Inputs: bboxes [N,4] f32 xyxy, labels [N] i32, priors [M,4] f32 cxcywh.
// Outputs (concat): reg_targets [M,4] f32, cls_targets [M] (written as f32).
//
// N = 1024, M = 49104. Grid (16 chunks, 96 prior-blocks, heavy-first).
// Block = 512 priors x 64 GTs:
//   - block bbox over the 512 prior boxes; wave 0 tests the 64 GTs: failing
//     GT => ALL pair-IoUs in this block are exactly 0.0f in the reference
//     (disjoint => clamped w/h == 0) => skipping is bit-exact.
//     ballot+prefix -> compacted ASCENDING list (box, area, idx) in LDS.
//   - per 8-row batch: phase 1: 2 IoUs/thread -> per-prior argmax regs +
//     LDS tile [8][520]; phase 2: 32 lanes per row scan transposed, 5-step
//     shfl merge with exact (max iou, min m) tie-break -> swin[gt] (LDS).
//   - epilogue: partGc[block][chunk-slice] = swin (0 for culled GTs);
//     part1c[chunk][m] = packed per-chunk argmax (plain store).
// Tie semantics == numpy everywhere: strict > over ascending index; packed
// u64 (iou_bits<<32)|(0xFFFFFFFF-idx): max == (max iou, smallest idx) and
// chunk index ranges are disjoint-ascending so u64 max over chunks == global
// first-max. Forced-assign duplicates: atomicMax(n) == numpy last-write-wins.
// Every GT overlaps a level-7 prior (512px boxes, centers 64..448) with
// iou > 0, so rs's 96-block reduce always finds a positive winner (zero
// partGc entries never win).

static constexpr float NEG_THRESH = 0.4f;
static constexpr float POS_THRESH = 0.5f;
static constexpr int N_GT = 1024;
static constexpr int GT_PER_BLK = 64;
static constexpr int NCHUNK = N_GT / GT_PER_BLK;   // 16
static constexpr int MPAD = 49152;                 // M rounded up to 512
static constexpr int BLK = 512;                    // priors per block
static constexpr int NB = MPAD / BLK;              // 96 prior blocks
static constexpr int T_ROWS = 8;                   // tile rows per batch
static constexpr int STRIDE = 520;                 // 520%32=8: 2-way max (free)

__device__ __forceinline__ unsigned long long packiou(float iou, unsigned idx_) {
    return ((unsigned long long)__float_as_uint(iou) << 32) |
           (unsigned long long)(0xFFFFFFFFu - idx_);
}

// ---------------- Fused kernel ----------------
__global__ void __launch_bounds__(256) fused_kernel(
        const float* __restrict__ bboxes,
        const float* __restrict__ priors,
        unsigned long long* __restrict__ part1c,   // [NCHUNK][MPAD] plain stores
        unsigned long long* __restrict__ partGc,   // [NB][N_GT] plain stores
        int* __restrict__ force_n,                 // [MPAD], chunk-0 blocks init
        int M) {
#pragma clang fp contract(off)
    __shared__ float tile[T_ROWS][STRIDE];         // 16.6 KB
    __shared__ float4 sgbox[GT_PER_BLK];
    __shared__ float2 sgmeta[GT_PER_BLK];          // (area, idx as float)
    __shared__ unsigned long long swin[GT_PER_BLK];
    __shared__ float sbb[4][4];
    __shared__ int scount;

    int tid = threadIdx.x;
    int lane = tid & 63;
    int wid = tid >> 6;
    int cx = blockIdx.x;                  // GT chunk
    int by = (NB - 1) - blockIdx.y;       // heavy levels dispatch first
    int n0 = cx * GT_PER_BLK;
    int m0 = by * BLK;
    int mA = m0 + tid;
    int mB = mA + 256;
    bool validA = (mA < M);
    bool validB = (mB < M);

    float4 pA = validA ? reinterpret_cast<const float4*>(priors)[mA]
                       : make_float4(0.f, 0.f, 0.f, 0.f);
    float4 pB = validB ? reinterpret_cast<const float4*>(priors)[mB]
                       : make_float4(0.f, 0.f, 0.f, 0.f);
    float ax1 = pA.x - pA.z / 2.0f, ay1 = pA.y - pA.w / 2.0f;
    float ax2 = pA.x + pA.z / 2.0f, ay2 = pA.y + pA.w / 2.0f;
    float areaA = (ax2 - ax1) * (ay2 - ay1);
    float bx1 = pB.x - pB.z / 2.0f, by1 = pB.y - pB.w / 2.0f;
    float bx2 = pB.x + pB.z / 2.0f, by2 = pB.y + pB.w / 2.0f;
    float areaB = (bx2 - bx1) * (by2 - by1);

    // ---- block bbox over the 512 prior boxes ----
    float mnx = validA ? ax1 : 1e30f;  if (validB) mnx = fminf(mnx, bx1);
    float mny = validA ? ay1 : 1e30f;  if (validB) mny = fminf(mny, by1);
    float mxx = validA ? ax2 : -1e30f; if (validB) mxx = fmaxf(mxx, bx2);
    float mxy = validA ? ay2 : -1e30f; if (validB) mxy = fmaxf(mxy, by2);
#pragma unroll
    for (int mk = 1; mk < 64; mk <<= 1) {
        mnx = fminf(mnx, __shfl_xor(mnx, mk));
        mny = fminf(mny, __shfl_xor(mny, mk));
        mxx = fmaxf(mxx, __shfl_xor(mxx, mk));
        mxy = fmaxf(mxy, __shfl_xor(mxy, mk));
    }
    if (lane == 0) {
        sbb[wid][0] = mnx; sbb[wid][1] = mny; sbb[wid][2] = mxx; sbb[wid][3] = mxy;
    }
    __syncthreads();

    // ---- wave 0: test 64 GTs, order-preserving compaction + swin init ----
    if (tid < 64) {
        float BX1 = fminf(fminf(sbb[0][0], sbb[1][0]), fminf(sbb[2][0], sbb[3][0]));
        float BY1 = fminf(fminf(sbb[0][1], sbb[1][1]), fminf(sbb[2][1], sbb[3][1]));
        float BX2 = fmaxf(fmaxf(sbb[0][2], sbb[1][2]), fmaxf(sbb[2][2], sbb[3][2]));
        float BY2 = fmaxf(fmaxf(sbb[0][3], sbb[1][3]), fmaxf(sbb[2][3], sbb[3][3]));
        float4 g = reinterpret_cast<const float4*>(bboxes)[n0 + tid];
        bool hit = (g.x < BX2) & (g.z > BX1) & (g.y < BY2) & (g.w > BY1);
        unsigned long long bal = __ballot(hit);
        if (hit) {
            int pos = __popcll(bal & ((1ull << tid) - 1ull));
            sgbox[pos] = g;
            sgmeta[pos] = make_float2((g.z - g.x) * (g.w - g.y), (float)tid);
        }
        if (tid == 0) scount = __popcll(bal);
        swin[tid] = 0ull;                 // per-call init (replay-safe)
    }
    __syncthreads();
    int cnt = scount;

    float bestA = 0.0f, bestB = 0.0f;     // iou >= 0 everywhere
    int bestnA = n0, bestnB = n0;         // all-zero chunk -> (0, n0)

    int row = tid >> 5;                   // phase-2: 32 lanes per row
    int sub = tid & 31;

    int nfull = cnt >> 3;
    int tail = cnt & 7;

    for (int b = 0; b <= nfull; ++b) {
        int rows = (b < nfull) ? T_ROWS : tail;
        if (rows == 0) break;
        int base = b * T_ROWS;

        // ---- phase 1: 2 IoUs per thread per row, packed GT broadcasts ----
#pragma unroll
        for (int r = 0; r < T_ROWS; ++r) {
            if (r < rows) {
                int idx = base + r;
                float4 gb = sgbox[idx];           // one b128 broadcast
                float2 mt = sgmeta[idx];          // one b64 broadcast
                int jn = n0 + (int)mt.y;

                float ltx = fmaxf(gb.x, ax1);
                float lty = fmaxf(gb.y, ay1);
                float rbx = fminf(gb.z, ax2);
                float rby = fminf(gb.w, ay2);
                float w = rbx - ltx; if (w < 0.0f) w = 0.0f;
                float h = rby - lty; if (h < 0.0f) h = 0.0f;
                float inter = w * h;
                float iouA = inter / (mt.x + areaA - inter);

                float ltx2 = fmaxf(gb.x, bx1);
                float lty2 = fmaxf(gb.y, by1);
                float rbx2 = fminf(gb.z, bx2);
                float rby2 = fminf(gb.w, by2);
                float w2 = rbx2 - ltx2; if (w2 < 0.0f) w2 = 0.0f;
                float h2 = rby2 - lty2; if (h2 < 0.0f) h2 = 0.0f;
                float inter2 = w2 * h2;
                float iouB = inter2 / (mt.x + areaB - inter2);

                // strict > over ascending idx (list ascending) == first-max
                if (iouA > bestA) { bestA = iouA; bestnA = jn; }
                if (iouB > bestB) { bestB = iouB; bestnB = jn; }
                tile[r][tid] = validA ? iouA : -1.0f;
                tile[r][tid + 256] = validB ? iouB : -1.0f;
            }
            // dead rows: nothing written; phase 2 never reads them
        }
        __syncthreads();

        // ---- phase 2: per-GT argmax over this block's 512 priors ----
        if (row < rows) {
            float bi = -2.0f;
            int bm = 0;
#pragma unroll
            for (int k = 0; k < BLK / 32; ++k) {
                int col = sub + 32 * k;             // ascending col per lane
                float v = tile[row][col];
                if (v > bi) { bi = v; bm = col; }   // strict >: smallest col
            }
#pragma unroll
            for (int msk = 1; msk < 32; msk <<= 1) { // 32-lane group merge
                float oi = __shfl_xor(bi, msk);
                int om = __shfl_xor(bm, msk);
                if (oi > bi || (oi == bi && om < bm)) { bi = oi; bm = om; }
            }
            if (sub == 0 && bi > 0.0f) {
                int jr = (int)sgmeta[base + row].y;
                swin[jr] = packiou(bi, (unsigned)(m0 + bm));
            }
        }
        __syncthreads();   // tile + swin reused/read next
    }

    // ---- epilogue: plain stores, no atomics ----
    if (tid < GT_PER_BLK) {
        partGc[(size_t)by * N_GT + n0 + tid] = swin[tid];
    }
    size_t rowc = (size_t)cx * MPAD;
    if (validA) part1c[rowc + mA] = packiou(bestA, (unsigned)bestnA);
    if (validB) part1c[rowc + mB] = packiou(bestB, (unsigned)bestnB);
    if (cx == 0) {
        if (validA) force_n[mA] = -1;   // rs runs after fused: safe init point
        if (validB) force_n[mB] = -1;
    }
}

// ---------------- RS: reduce partGc over blocks -> forced-assign scatter -----
__global__ void rs_kernel(const unsigned long long* __restrict__ partGc,
                          int* __restrict__ force_n) {
    int n = blockIdx.x * blockDim.x + threadIdx.x;
    if (n >= N_GT) return;
    unsigned long long best = 0ull;
    for (int c = 0; c < NB; ++c) {            // lanes read adjacent n: coalesced
        unsigned long long v = partGc[(size_t)c * N_GT + n];
        if (v > best) best = v;
    }
    // best > 0 guaranteed: every GT overlaps a level-7 prior with iou > 0
    int m = (int)(0xFFFFFFFFu - (unsigned)(best & 0xFFFFFFFFull));
    atomicMax(&force_n[m], n);   // duplicate priors: last write in np == max n
}

// ---------------- E: reduce part1c over chunks + encode ----------------------
__global__ void __launch_bounds__(256) encode_kernel(
        const float* __restrict__ bboxes,
        const int* __restrict__ labels,
        const float* __restrict__ priors,
        const unsigned long long* __restrict__ part1c,
        const int* __restrict__ force_n,
        float* __restrict__ out, int M) {
#pragma clang fp contract(off)
    int m = blockIdx.x * 256 + threadIdx.x;
    if (m >= M) return;

    unsigned long long best = part1c[m];
    for (int c = 1; c < NCHUNK; ++c) {
        unsigned long long v = part1c[(size_t)c * MPAD + m];
        if (v > best) best = v;   // u64 max == (max iou, smallest global n)
    }
    float iou = __uint_as_float((unsigned)(best >> 32));
    int mid = (int)(0xFFFFFFFFu - (unsigned)(best & 0xFFFFFFFFull));

    int f = force_n[m];
    if (f >= 0) { mid = f; iou = POS_THRESH; }

    float4 g = reinterpret_cast<const float4*>(bboxes)[mid];
    float mcx = (g.x + g.z) / 2.0f;
    float mcy = (g.y + g.w) / 2.0f;
    float mw = g.z - g.x;
    float mh = g.w - g.y;

    float4 p = reinterpret_cast<const float4*>(priors)[m];
    float dcx = ((mcx - p.x) / p.z) / 0.1f;
    float dcy = ((mcy - p.y) / p.w) / 0.1f;
    float dw = logf(mw / p.z) / 0.2f;
    float dh = logf(mh / p.w) / 0.2f;

    reinterpret_cast<float4*>(out)[m] = make_float4(dcx, dcy, dw, dh);

    int cls = labels[mid];
    if (iou < POS_THRESH) cls = -1;
    if (iou < NEG_THRESH) cls = 0;
    out[(size_t)4 * M + m] = (float)cls;
}

extern "C" void kernel_launch(void* const* d_in, const int* in_sizes, int n_in,
                              void* d_out, int out_size, void* d_ws, size_t ws_size,
                              hipStream_t stream) {
    const float* bboxes = (const float*)d_in[0];
    const int* labels = (const int*)d_in[1];
    const float* priors = (const float*)d_in[2];
    int M = in_sizes[2] / 4;
    float* out = (float*)d_out;

    // Workspace (~7.3 MB): part1c [16][MPAD] u64 | partGc [96][N_GT] u64 |
    //                      force_n [MPAD] int
    char* ws = (char*)d_ws;
    unsigned long long* part1c = (unsigned long long*)ws;
    unsigned long long* partGc =
        (unsigned long long*)(ws + (size_t)NCHUNK * MPAD * 8);
    int* force_n =
        (int*)(ws + (size_t)NCHUNK * MPAD * 8 + (size_t)NB * N_GT * 8);

    fused_kernel<<<dim3(NCHUNK, NB), 256, 0, stream>>>(bboxes, priors, part1c,
                                                       partGc, force_n, M);
    rs_kernel<<<(N_GT + 255) / 256, 256, 0, stream>>>(partGc, force_n);
    encode_kernel<<<(MPAD + 255) / 256, 256, 0, stream>>>(bboxes, labels, priors,
                                                          part1c, force_n, out, M);
}

// Round 15
// 34.580 us; speedup vs baseline: 1.3268x; 1.3268x over previous
//
#include <hip/hip_runtime.h>

// RetinaNet target encoder for MI355X — round 15: round-12 base (best: 38.3us)
// + two-level cull: block-level compaction (as before) PLUS a per-wave
// secondary mask over the compacted list — rows culled for a wave cost one
// -1 store instead of a full IoU. GT data packed (float4 + float2) so live
// rows do 2 LDS broadcasts instead of 6.
//
// Inputs: bboxes [N,4] f32 xyxy, labels [N] i32, priors [M,4] f32 cxcywh.
// Outputs (concat): reg_targets [M,4] f32, cls_targets [M] (written as f32).
//
// N = 1024, M = 49104. Grid (16 chunks, 192 prior-blocks, heavy-first).
// Block = 256 priors x 64 GTs:
//   - per-wave bbox (butterfly, kept in regs) -> block bbox (LDS reduce)
//   - wave 0: block-bbox test + ballot+prefix -> compacted ASCENDING list of
//     (box float4, (area, idx) float2) in LDS. Failing GT => ALL pair-IoUs
//     in this block are exactly 0.0f (disjoint => clamped w/h == 0) => exact.
//   - each wave ballots the compacted list vs its own bbox -> wavemask SGPR.
//     Clear bit => IoU == 0.0f for all 64 of this wave's priors => exact skip
//     (phase 1 writes -1; -1 rows/segments never beat real IoUs >= 0, and an
//     all--1 row gives bi <= 0 -> no partG write; zeros never win globally).
//   - per 16-row batch: phase 1: live rows IoU -> per-prior argmax regs +
//     LDS tile; phase 2: 16 lanes/row transposed scan, 4-step shfl merge,
//     exact (max iou, min m) tie-break -> atomicMax partG[gt].
// Tie semantics == numpy everywhere: strict > over ascending index; packed
// u64 (iou_bits<<32)|(0xFFFFFFFF-idx) max == (max iou, smallest idx);
// forced-assign duplicates: atomicMax(n) == numpy last-write-wins.
// part1 init = packiou(0,0): all-zero prior row decodes to (0, 0) = numpy
// argmax over zeros; best==0 chunks skip their atomic (can't beat init).

static constexpr float NEG_THRESH = 0.4f;
static constexpr float POS_THRESH = 0.5f;
static constexpr int N_GT = 1024;
static constexpr int GT_PER_BLK = 64;
static constexpr int NCHUNK = N_GT / GT_PER_BLK;   // 16
static constexpr int MPAD = 49152;                 // M rounded up to 256
static constexpr int BLK = 256;                    // priors per block
static constexpr int NB = MPAD / BLK;              // 192 prior blocks
static constexpr int T_ROWS = 16;                  // tile rows per batch
static constexpr int STRIDE = 264;                 // 2-way banks max (free)

__device__ __forceinline__ unsigned long long packiou(float iou, unsigned idx_) {
    return ((unsigned long long)__float_as_uint(iou) << 32) |
           (unsigned long long)(0xFFFFFFFFu - idx_);
}

// ---------------- Init: tiny, replaces hipMemsetAsync ------------------------
__global__ void __launch_bounds__(256) init_kernel(
        unsigned long long* __restrict__ part1,
        unsigned long long* __restrict__ partG,
        int* __restrict__ force_n) {
    int i = blockIdx.x * 256 + threadIdx.x;
    part1[i] = 0x00000000FFFFFFFFull;   // packiou(0.0f, 0)
    force_n[i] = -1;
    if (i < N_GT) partG[i] = 0ull;
}

// ---------------- Fused kernel ----------------
__global__ void __launch_bounds__(256) fused_kernel(
        const float* __restrict__ bboxes,
        const float* __restrict__ priors,
        unsigned long long* __restrict__ part1,   // [MPAD] init packiou(0,0)
        unsigned long long* __restrict__ partG,   // [N_GT] init 0, atomicMax
        int M) {
#pragma clang fp contract(off)
    __shared__ float tile[T_ROWS][STRIDE];        // 16.9 KB
    __shared__ float4 sgbox[GT_PER_BLK];
    __shared__ float2 sgmeta[GT_PER_BLK];         // (area, idx as float)
    __shared__ float sbb[4][4];
    __shared__ int scount;

    int tid = threadIdx.x;
    int lane = tid & 63;
    int wid = tid >> 6;
    int bx = (NB - 1) - blockIdx.y;               // heavy levels dispatch first
    int n0 = blockIdx.x * GT_PER_BLK;
    int m = bx * BLK + tid;
    bool valid = (m < M);

    float4 p = valid ? reinterpret_cast<const float4*>(priors)[m]
                     : make_float4(0.f, 0.f, 0.f, 0.f);
    float bx1 = p.x - p.z / 2.0f;
    float by1 = p.y - p.w / 2.0f;
    float bx2 = p.x + p.z / 2.0f;
    float by2 = p.y + p.w / 2.0f;
    float area_b = (bx2 - bx1) * (by2 - by1);

    // ---- per-wave bbox over 64 priors (stays in registers for the
    //      secondary cull), then block bbox via LDS ----
    float mnx = valid ? bx1 : 1e30f;
    float mny = valid ? by1 : 1e30f;
    float mxx = valid ? bx2 : -1e30f;
    float mxy = valid ? by2 : -1e30f;
#pragma unroll
    for (int mk = 1; mk < 64; mk <<= 1) {
        mnx = fminf(mnx, __shfl_xor(mnx, mk));
        mny = fminf(mny, __shfl_xor(mny, mk));
        mxx = fmaxf(mxx, __shfl_xor(mxx, mk));
        mxy = fmaxf(mxy, __shfl_xor(mxy, mk));
    }
    if (lane == 0) {
        sbb[wid][0] = mnx; sbb[wid][1] = mny; sbb[wid][2] = mxx; sbb[wid][3] = mxy;
    }
    __syncthreads();

    // ---- wave 0: block-bbox test of 64 GTs, ascending compaction ----
    if (tid < 64) {
        float BX1 = fminf(fminf(sbb[0][0], sbb[1][0]), fminf(sbb[2][0], sbb[3][0]));
        float BY1 = fminf(fminf(sbb[0][1], sbb[1][1]), fminf(sbb[2][1], sbb[3][1]));
        float BX2 = fmaxf(fmaxf(sbb[0][2], sbb[1][2]), fmaxf(sbb[2][2], sbb[3][2]));
        float BY2 = fmaxf(fmaxf(sbb[0][3], sbb[1][3]), fmaxf(sbb[2][3], sbb[3][3]));
        float4 g = reinterpret_cast<const float4*>(bboxes)[n0 + tid];
        bool hit = (g.x < BX2) & (g.z > BX1) & (g.y < BY2) & (g.w > BY1);
        unsigned long long bal = __ballot(hit);
        if (hit) {
            int pos = __popcll(bal & ((1ull << tid) - 1ull));
            sgbox[pos] = g;
            sgmeta[pos] = make_float2((g.z - g.x) * (g.w - g.y), (float)tid);
        }
        if (tid == 0) scount = __popcll(bal);
    }
    __syncthreads();
    int cnt = scount;

    // ---- per-wave secondary mask over the compacted list (one ballot) ----
    // Value for lane >= cnt is stale/uninitialized LDS but masked out below.
    float4 gl = sgbox[lane & 63];
    bool hw = (lane < cnt) & (gl.x < mxx) & (gl.z > mnx) &
              (gl.y < mxy) & (gl.w > mny);
    unsigned long long wavemask = __ballot(hw);   // wave-uniform SGPR

    float best = 0.0f;    // iou >= 0 everywhere
    int bestn = n0;

    int row = tid >> 4;   // phase-2: 16 lanes per row
    int sub = tid & 15;
    int m0 = bx * BLK;

    int nfull = cnt >> 4;
    int tail = cnt & 15;

    for (int b = 0; b <= nfull; ++b) {
        int rows = (b < nfull) ? T_ROWS : tail;
        if (rows == 0) break;
        int base = b * T_ROWS;

        // ---- phase 1: live rows full IoU; wave-culled rows one -1 store ----
#pragma unroll
        for (int r = 0; r < T_ROWS; ++r) {
            if (r < rows) {
                int idx = base + r;
                if ((wavemask >> idx) & 1) {      // wave-uniform scalar branch
                    float4 gb = sgbox[idx];       // one b128 broadcast
                    float2 mt = sgmeta[idx];      // one b64 broadcast
                    int jn = n0 + (int)mt.y;

                    float ltx = fmaxf(gb.x, bx1);
                    float lty = fmaxf(gb.y, by1);
                    float rbx = fminf(gb.z, bx2);
                    float rby = fminf(gb.w, by2);
                    float w = rbx - ltx; if (w < 0.0f) w = 0.0f;
                    float h = rby - lty; if (h < 0.0f) h = 0.0f;
                    float inter = w * h;
                    float iou = inter / (mt.x + area_b - inter);

                    // strict > over ascending idx == numpy first-max
                    if (iou > best) { best = iou; bestn = jn; }
                    tile[r][tid] = valid ? iou : -1.0f;
                } else {
                    // GT disjoint from this wave's bbox: all 64 IoUs == 0.0f
                    tile[r][tid] = -1.0f;
                }
            } else {
                tile[r][tid] = -1.0f;             // dead row
            }
        }
        __syncthreads();

        // ---- phase 2: per-GT argmax over this block's 256 priors ----
        float bi = -2.0f;
        int bm = 0;
#pragma unroll
        for (int k = 0; k < BLK / 16; ++k) {
            int col = sub + 16 * k;               // ascending col per lane
            float v = tile[row][col];
            if (v > bi) { bi = v; bm = col; }     // strict >: smallest col
        }
#pragma unroll
        for (int msk = 1; msk < 16; msk <<= 1) {  // 16-lane group merge
            float oi = __shfl_xor(bi, msk);
            int om = __shfl_xor(bm, msk);
            if (oi > bi || (oi == bi && om < bm)) { bi = oi; bm = om; }
        }
        if (sub == 0 && bi > 0.0f) {
            // bi > 0 => live row with a real winner (culled segments are -1,
            // real IoUs >= 0; all-culled row gives bi <= 0 -> skipped)
            int jr = (int)sgmeta[base + row].y;
            atomicMax(&partG[n0 + jr], packiou(bi, (unsigned)(m0 + bm)));
        }
        __syncthreads();   // tile reused next batch
    }

    // best == 0 chunks skip: init packiou(0,0) >= packiou(0,n) for all n >= 0.
    if (valid && best > 0.0f) {
        atomicMax(&part1[m], packiou(best, (unsigned)bestn));
    }
}

// ---------------- RS: per-GT winner -> forced-assignment scatter -------------
__global__ void rs_kernel(const unsigned long long* __restrict__ partG,
                          int* __restrict__ force_n) {
    int n = blockIdx.x * blockDim.x + threadIdx.x;
    if (n >= N_GT) return;
    unsigned long long v = partG[n];
    int m = (int)(0xFFFFFFFFu - (unsigned)(v & 0xFFFFFFFFull));
    atomicMax(&force_n[m], n);   // duplicate priors: last write in np == max n
}

// ---------------- E: decode per-prior winner + encode ------------------------
__global__ void __launch_bounds__(256) encode_kernel(
        const float* __restrict__ bboxes,
        const int* __restrict__ labels,
        const float* __restrict__ priors,
        const unsigned long long* __restrict__ part1,
        const int* __restrict__ force_n,
        float* __restrict__ out, int M) {
#pragma clang fp contract(off)
    int m = blockIdx.x * 256 + threadIdx.x;
    if (m >= M) return;

    unsigned long long v = part1[m];
    float iou = __uint_as_float((unsigned)(v >> 32));
    int mid = (int)(0xFFFFFFFFu - (unsigned)(v & 0xFFFFFFFFull));

    int f = force_n[m];
    if (f >= 0) { mid = f; iou = POS_THRESH; }

    float4 g = reinterpret_cast<const float4*>(bboxes)[mid];
    float mcx = (g.x + g.z) / 2.0f;
    float mcy = (g.y + g.w) / 2.0f;
    float mw = g.z - g.x;
    float mh = g.w - g.y;

    float4 p = reinterpret_cast<const float4*>(priors)[m];
    float dcx = ((mcx - p.x) / p.z) / 0.1f;
    float dcy = ((mcy - p.y) / p.w) / 0.1f;
    float dw = logf(mw / p.z) / 0.2f;
    float dh = logf(mh / p.w) / 0.2f;

    reinterpret_cast<float4*>(out)[m] = make_float4(dcx, dcy, dw, dh);

    int cls = labels[mid];
    if (iou < POS_THRESH) cls = -1;
    if (iou < NEG_THRESH) cls = 0;
    out[(size_t)4 * M + m] = (float)cls;
}

extern "C" void kernel_launch(void* const* d_in, const int* in_sizes, int n_in,
                              void* d_out, int out_size, void* d_ws, size_t ws_size,
                              hipStream_t stream) {
    const float* bboxes = (const float*)d_in[0];
    const int* labels = (const int*)d_in[1];
    const float* priors = (const float*)d_in[2];
    int M = in_sizes[2] / 4;
    float* out = (float*)d_out;

    // Workspace (~0.6 MB): part1 [MPAD u64] | partG [N_GT u64] | force_n [MPAD int]
    char* ws = (char*)d_ws;
    unsigned long long* part1 = (unsigned long long*)ws;
    unsigned long long* partG = (unsigned long long*)(ws + (size_t)MPAD * 8);
    int* force_n = (int*)(ws + (size_t)MPAD * 8 + (size_t)N_GT * 8);

    init_kernel<<<MPAD / 256, 256, 0, stream>>>(part1, partG, force_n);
    fused_kernel<<<dim3(NCHUNK, NB), 256, 0, stream>>>(bboxes, priors, part1,
                                                       partG, M);
    rs_kernel<<<(N_GT + 255) / 256, 256, 0, stream>>>(partG, force_n);
    encode_kernel<<<(MPAD + 255) / 256, 256, 0, stream>>>(bboxes, labels, priors,
                                                          part1, force_n, out, M);
}